// Round 13
// baseline (168.346 us; speedup 1.0000x reference)
//
#include <hip/hip_runtime.h>
#include <hip/hip_bf16.h>
#include <cstdint>
#include <cstddef>

#define B_DIM 32
#define S_DIM 1024
#define H_DIM 1024
#define M_DIM (B_DIM * S_DIM)   // 32768

typedef __attribute__((ext_vector_type(8))) short bf16x8;
typedef __attribute__((ext_vector_type(4))) float f32x4;

// round-to-nearest-even fp32 -> bf16 (bit trick; no NaN inputs here)
static __device__ __forceinline__ unsigned short f2bf(float f) {
  unsigned u = __float_as_uint(f);
  u = (u + 0x7FFFu + ((u >> 16) & 1u)) >> 16;
  return (unsigned short)u;
}
static __device__ __forceinline__ float bf2f(unsigned short u) {
  return __uint_as_float(((unsigned)u) << 16);
}
// exact identity tanh(x) = 1 - 2/(exp(2x)+1)
static __device__ __forceinline__ float fast_tanh(float x) {
  return 1.f - 2.f / (__expf(2.f * x) + 1.f);
}

// async global(16B/lane) -> LDS, wave-uniform LDS base, per-lane global addr
static __device__ __forceinline__ void gload16(const unsigned short* g, char* l) {
  __builtin_amdgcn_global_load_lds(
      (const __attribute__((address_space(1))) unsigned int*)g,
      (__attribute__((address_space(3))) unsigned int*)l, 16, 0, 0);
}

// ---------------- K_prep_all ----------------
// Blocks 0..1023: U_h (latency-bound, FIRST so it overlaps the convert).
// Blocks 1024..2047: W -> bf16. Blocks 2048..4095: enc -> bf16 (grid-stride).
__global__ void k_prep_all(const float* __restrict__ E, unsigned short* __restrict__ Eb,
                           const float* __restrict__ W, unsigned short* __restrict__ Wb,
                           const float* __restrict__ dh, const float* __restrict__ Uw,
                           float* __restrict__ Uh) {
  const int bid = blockIdx.x;
  if (bid < 1024) {
    const int wave = threadIdx.x >> 6;
    const int lane = threadIdx.x & 63;
    const int o = bid;                                 // 0..1023
    float uw[16];
#pragma unroll
    for (int k = 0; k < 16; ++k) uw[k] = Uw[o * H_DIM + k * 64 + lane];
#pragma unroll
    for (int bb = 0; bb < 8; ++bb) {
      const int b = wave * 8 + bb;                     // 0..31
      float acc = 0.f;
#pragma unroll
      for (int k = 0; k < 16; ++k) acc += uw[k] * dh[b * H_DIM + k * 64 + lane];
#pragma unroll
      for (int msk = 32; msk >= 1; msk >>= 1) acc += __shfl_xor(acc, msk, 64);
      if (lane == 0) Uh[b * H_DIM + o] = acc;
    }
  } else if (bid < 2048) {
    const int idx = (bid - 1024) * 256 + threadIdx.x;  // 0 .. 262143
    float4 v = ((const float4*)W)[idx];
    ushort4 o;
    o.x = f2bf(v.x); o.y = f2bf(v.y); o.z = f2bf(v.z); o.w = f2bf(v.w);
    ((ushort4*)Wb)[idx] = o;
  } else {
    const int n8 = M_DIM * (H_DIM / 8);                // 4,194,304 chunks
    const int stride = 2048 * 256;
    for (int idx = (bid - 2048) * 256 + threadIdx.x; idx < n8; idx += stride) {
      const float4* gp = (const float4*)(E + (size_t)idx * 8);
      float4 lo = gp[0], hi = gp[1];
      bf16x8 w;
      w[0] = (short)f2bf(lo.x); w[1] = (short)f2bf(lo.y);
      w[2] = (short)f2bf(lo.z); w[3] = (short)f2bf(lo.w);
      w[4] = (short)f2bf(hi.x); w[5] = (short)f2bf(hi.y);
      w[6] = (short)f2bf(hi.z); w[7] = (short)f2bf(hi.w);
      *(bf16x8*)(Eb + (size_t)idx * 8) = w;
    }
  }
}

// ---------------- K2: 256x256, A via LDS-DMA, B direct from L2 ----------------
// BM=256, BN=256, BK=64. 512 threads = 8 waves (2M x 4N), per-wave 128x64 tile.
// LDS: 2 buffers x 32KB (A only) = 64KB. B (2MB, L2-resident) is loaded per-lane
// straight to registers on the VMEM pipe, removing ~1024cy/K-tile of B traffic
// from the serialized LDS pipe (ds_read + DMA-write).
#define A5_BM 256
#define A5_BN 256
#define A10_BUF 32768
#define NT_FAST 4      // n_tiles

__launch_bounds__(512, 2)
__global__ void k_att10(const unsigned short* __restrict__ Eb,
                        const unsigned short* __restrict__ Wb,
                        const float* __restrict__ Uh,
                        const float* __restrict__ vw,
                        float* __restrict__ att_p) {
  __shared__ __align__(16) char lds[2 * A10_BUF];   // 64 KB

  // XCD-friendly: blocks with same (bid&7) sit on one XCD
  const int bid = blockIdx.x;            // 0..511
  const int xj = bid & 7;
  const int q  = bid >> 3;               // 0..63
  const int n_tile = q & 3;              // 0..3
  const int m_tile = ((q >> 2) << 3) | xj;   // 0..127, bijective
  const int m0 = m_tile * A5_BM;
  const int n0 = n_tile * A5_BN;
  const int b  = m0 >> 10;

  const int tid  = threadIdx.x;          // 0..511
  const int wid  = tid >> 6;             // 0..7
  const int lane = tid & 63;
  const int wm = (wid >> 2) * 128;       // 0 / 128 (per-wave 128 rows)
  const int wn = (wid & 3) * 64;         // 0,64,128,192 (per-wave 64 cols)

  // A staging map (linear LDS dest; inverse-swizzled global source; swizzled reads)
  size_t offA[4];
  int ldsA[4];
#pragma unroll
  for (int j = 0; j < 4; ++j) {
    const int chunk = j * 512 + tid;     // 0..2047 -> rows 0..255
    const int r  = chunk >> 3;
    const int c8 = (chunk & 7) ^ (r & 7);
    offA[j] = (size_t)(m0 + r) * H_DIM + c8 * 8;
    ldsA[j] = j * 8192 + wid * 1024;
  }

  auto stage = [&](int t) {              // 4 A-DMA loads -> buf (t&1)
    char* dst = lds + (t & 1) * A10_BUF;
    const size_t k0 = (size_t)t * 64;
#pragma unroll
    for (int j = 0; j < 4; ++j) gload16(Eb + offA[j] + k0, dst + ldsA[j]);
  };

  const int fr_row = lane & 15;
  const int fr_k8  = lane >> 4;

  // B row pointers: lane holds W[o = n0+wn+nf*16+fr_row][k = fr_k8*8 ..], per-tile +64
  const unsigned short* bp[4];
#pragma unroll
  for (int nf = 0; nf < 4; ++nf)
    bp[nf] = Wb + (size_t)(n0 + wn + nf * 16 + fr_row) * H_DIM + fr_k8 * 8;

  f32x4 acc[8][4];
#pragma unroll
  for (int mf = 0; mf < 8; ++mf)
#pragma unroll
    for (int nf = 0; nf < 4; ++nf) acc[mf][nf] = (f32x4)(0.0f);

  stage(0);                              // 4 A-loads in flight

  for (int t = 0; t < 16; ++t) {
    // A-DMAs for tile t were issued a full K-tile ago -> drain ~free.
    asm volatile("s_waitcnt vmcnt(0)" ::: "memory");
    __builtin_amdgcn_s_barrier();
    asm volatile("" ::: "memory");       // keep ds_reads below the barrier

    // B frags for tile t: issue BEFORE the next A-DMA so the compiler's
    // auto-vmcnt for their uses leaves the DMA in flight.
    bf16x8 bfr[4][2];
#pragma unroll
    for (int nf = 0; nf < 4; ++nf)
#pragma unroll
      for (int kh = 0; kh < 2; ++kh)
        bfr[nf][kh] = *(const bf16x8*)(bp[nf] + (size_t)t * 64 + kh * 32);
    __builtin_amdgcn_sched_barrier(0);   // pin: B loads stay above the DMA

    if (t < 15) stage(t + 1);            // writes buf[(t+1)&1], protected by barrier

    const char* As = lds + (t & 1) * A10_BUF;

#pragma unroll
    for (int kh = 0; kh < 2; ++kh) {
      const int kb = kh * 32 + fr_k8 * 8;
      bf16x8 af[8];
#pragma unroll
      for (int mf = 0; mf < 8; ++mf) {
        const int row = wm + mf * 16 + fr_row;               // 0..255
        const int addr = (row * 128 + kb * 2) ^ ((row & 7) << 4);
        af[mf] = *(const bf16x8*)(As + addr);
      }
      __builtin_amdgcn_s_setprio(1);
#pragma unroll
      for (int mf = 0; mf < 8; ++mf)
#pragma unroll
        for (int nf = 0; nf < 4; ++nf)
          acc[mf][nf] = __builtin_amdgcn_mfma_f32_16x16x32_bf16(af[mf], bfr[nf][kh], acc[mf][nf], 0, 0, 0);
      __builtin_amdgcn_s_setprio(0);
    }
  }

  float* red = (float*)lds;   // [8 waves][128 rows] = 4KB in buf0; t=15 read buf1 -> safe

  // Epilogue: tanh(acc + Uh)*v, reduce over this wave's 64 o's.
  // D frag: col = lane&15 (n), row = (lane>>4)*4 + reg (m)
  const int col = lane & 15;
  const int rhi = lane >> 4;
  float uh[4], vv[4];
#pragma unroll
  for (int nf = 0; nf < 4; ++nf) {
    const int o = n0 + wn + nf * 16 + col;
    uh[nf] = Uh[b * H_DIM + o];
    vv[nf] = vw[o];
  }
#pragma unroll
  for (int mf = 0; mf < 8; ++mf) {
    float rs[4];
#pragma unroll
    for (int jj = 0; jj < 4; ++jj) {
      float s = 0.f;
#pragma unroll
      for (int nf = 0; nf < 4; ++nf) {
        const float x = acc[mf][nf][jj] + uh[nf];
        s += fast_tanh(x) * vv[nf];
      }
      rs[jj] = s;
    }
#pragma unroll
    for (int msk = 1; msk < 16; msk <<= 1) {
#pragma unroll
      for (int jj = 0; jj < 4; ++jj) rs[jj] += __shfl_xor(rs[jj], msk, 64);
    }
    if (col == 0) {
#pragma unroll
      for (int jj = 0; jj < 4; ++jj) {
        const int local = mf * 16 + rhi * 4 + jj;   // row within wave's 128
        red[wid * 128 + local] = rs[jj];
      }
    }
  }
  __syncthreads();
  if (tid < 256) {
    const int mhalf = tid >> 7;          // waves {0..3} own rows 0..127, {4..7} rows 128..255
    const int loc = tid & 127;
    float sum = 0.f;
#pragma unroll
    for (int j = 0; j < 4; ++j) sum += red[(mhalf * 4 + j) * 128 + loc];
    att_p[(size_t)n_tile * M_DIM + m0 + tid] = sum;
  }
}

// ---------------- K3: fused softmax + context partials ----------------
__global__ void k_ctx_sm(const unsigned short* __restrict__ Eb,
                         const float* __restrict__ att_p,
                         float* __restrict__ alpha_out,
                         float* __restrict__ ctx_p) {
  const int bid = blockIdx.x;
  const int b  = bid >> 2;
  const int sq = bid & 3;
  const int tid = threadIdx.x;
  __shared__ float red[8];
  __shared__ float qa[256];

  float a[4];
  float mx = -1e30f;
#pragma unroll
  for (int i = 0; i < 4; ++i) {
    const int s = i * 256 + tid;
    float v = 0.f;
#pragma unroll
    for (int t = 0; t < NT_FAST; ++t) v += att_p[(size_t)t * M_DIM + b * S_DIM + s];
    a[i] = v;
    mx = fmaxf(mx, v);
  }
#pragma unroll
  for (int msk = 32; msk >= 1; msk >>= 1) mx = fmaxf(mx, __shfl_xor(mx, msk, 64));
  if ((tid & 63) == 0) red[tid >> 6] = mx;
  __syncthreads();
  mx = fmaxf(fmaxf(red[0], red[1]), fmaxf(red[2], red[3]));
  float sum = 0.f;
#pragma unroll
  for (int i = 0; i < 4; ++i) { a[i] = __expf(a[i] - mx); sum += a[i]; }
#pragma unroll
  for (int msk = 32; msk >= 1; msk >>= 1) sum += __shfl_xor(sum, msk, 64);
  if ((tid & 63) == 0) red[4 + (tid >> 6)] = sum;
  __syncthreads();
  const float inv = 1.f / (red[4] + red[5] + red[6] + red[7]);
  if (sq == 0) {
#pragma unroll
    for (int i = 0; i < 4; ++i) alpha_out[b * S_DIM + i * 256 + tid] = a[i] * inv;
  }
  qa[tid] = a[sq] * inv;
  __syncthreads();

  const int h = tid * 4;
  const unsigned short* ep = Eb + (size_t)b * S_DIM * H_DIM + (size_t)(sq * 256) * H_DIM + h;
  float4 acc = make_float4(0.f, 0.f, 0.f, 0.f);
  for (int s = 0; s < 256; ++s) {
    const float al = qa[s];
    ushort4 v = *(const ushort4*)(ep + (size_t)s * H_DIM);
    acc.x += al * bf2f(v.x);
    acc.y += al * bf2f(v.y);
    acc.z += al * bf2f(v.z);
    acc.w += al * bf2f(v.w);
  }
  *(float4*)&ctx_p[(size_t)sq * (B_DIM * H_DIM) + b * H_DIM + h] = acc;
}

// ---------------- K5: reduce context partials -> d_out ----------------
__global__ void k_ctx_reduce(const float* __restrict__ ctx_p, float* __restrict__ ctx) {
  const int i = blockIdx.x * 256 + threadIdx.x;
  ctx[i] = ctx_p[i] + ctx_p[32768 + i] + ctx_p[65536 + i] + ctx_p[98304 + i];
}

extern "C" void kernel_launch(void* const* d_in, const int* in_sizes, int n_in,
                              void* d_out, int out_size, void* d_ws, size_t ws_size,
                              hipStream_t stream) {
  (void)in_sizes; (void)n_in; (void)out_size; (void)ws_size;
  const float* dh  = (const float*)d_in[0];
  const float* enc = (const float*)d_in[1];
  const float* Uw  = (const float*)d_in[2];
  const float* Ww  = (const float*)d_in[3];
  const float* vw  = (const float*)d_in[4];
  float* ctx_out = (float*)d_out;                 // [32,1024]
  float* alpha   = (float*)d_out + M_DIM;         // [32,1024]

  char* ws = (char*)d_ws;
  const size_t EB_BYTES = (size_t)M_DIM * H_DIM * 2;            // 64 MiB

  unsigned short* Eb = (unsigned short*)ws;
  unsigned short* Wb = (unsigned short*)(ws + EB_BYTES);
  float* Uh    = (float*)(ws + EB_BYTES + (2u << 20));
  float* att_p = (float*)(ws + EB_BYTES + (2u << 20) + (128u << 10));
  float* ctx_p = (float*)(ws + EB_BYTES + (2u << 20) + (128u << 10) + (1u << 20));

  k_prep_all<<<4096, 256, 0, stream>>>(enc, Eb, Ww, Wb, dh, Uw, Uh);
  k_att10<<<512, 512, 0, stream>>>(Eb, Wb, Uh, vw, att_p);
  k_ctx_sm<<<128, 256, 0, stream>>>(Eb, att_p, alpha, ctx_p);
  k_ctx_reduce<<<128, 256, 0, stream>>>(ctx_p, ctx_out);
}

// Round 14
// 141.209 us; speedup vs baseline: 1.1922x; 1.1922x over previous
//
#include <hip/hip_runtime.h>
#include <hip/hip_bf16.h>
#include <cstdint>
#include <cstddef>

#define B_DIM 32
#define S_DIM 1024
#define H_DIM 1024
#define M_DIM (B_DIM * S_DIM)   // 32768

typedef __attribute__((ext_vector_type(8))) short bf16x8;
typedef __attribute__((ext_vector_type(4))) float f32x4;
typedef __attribute__((ext_vector_type(16))) float f32x16;

// round-to-nearest-even fp32 -> bf16 (bit trick; no NaN inputs here)
static __device__ __forceinline__ unsigned short f2bf(float f) {
  unsigned u = __float_as_uint(f);
  u = (u + 0x7FFFu + ((u >> 16) & 1u)) >> 16;
  return (unsigned short)u;
}
static __device__ __forceinline__ float bf2f(unsigned short u) {
  return __uint_as_float(((unsigned)u) << 16);
}
// exact identity tanh(x) = 1 - 2/(exp(2x)+1)
static __device__ __forceinline__ float fast_tanh(float x) {
  return 1.f - 2.f / (__expf(2.f * x) + 1.f);
}

// async global(16B/lane) -> LDS, wave-uniform LDS base, per-lane global addr
static __device__ __forceinline__ void gload16(const unsigned short* g, char* l) {
  __builtin_amdgcn_global_load_lds(
      (const __attribute__((address_space(1))) unsigned int*)g,
      (__attribute__((address_space(3))) unsigned int*)l, 16, 0, 0);
}

// ---------------- K_prep_all ----------------
// Blocks 0..1023: U_h (latency-bound, FIRST so it overlaps the convert).
// Blocks 1024..2047: W -> bf16. Blocks 2048..4095: enc -> bf16 (grid-stride).
__global__ void k_prep_all(const float* __restrict__ E, unsigned short* __restrict__ Eb,
                           const float* __restrict__ W, unsigned short* __restrict__ Wb,
                           const float* __restrict__ dh, const float* __restrict__ Uw,
                           float* __restrict__ Uh) {
  const int bid = blockIdx.x;
  if (bid < 1024) {
    const int wave = threadIdx.x >> 6;
    const int lane = threadIdx.x & 63;
    const int o = bid;                                 // 0..1023
    float uw[16];
#pragma unroll
    for (int k = 0; k < 16; ++k) uw[k] = Uw[o * H_DIM + k * 64 + lane];
#pragma unroll
    for (int bb = 0; bb < 8; ++bb) {
      const int b = wave * 8 + bb;                     // 0..31
      float acc = 0.f;
#pragma unroll
      for (int k = 0; k < 16; ++k) acc += uw[k] * dh[b * H_DIM + k * 64 + lane];
#pragma unroll
      for (int msk = 32; msk >= 1; msk >>= 1) acc += __shfl_xor(acc, msk, 64);
      if (lane == 0) Uh[b * H_DIM + o] = acc;
    }
  } else if (bid < 2048) {
    const int idx = (bid - 1024) * 256 + threadIdx.x;  // 0 .. 262143
    float4 v = ((const float4*)W)[idx];
    ushort4 o;
    o.x = f2bf(v.x); o.y = f2bf(v.y); o.z = f2bf(v.z); o.w = f2bf(v.w);
    ((ushort4*)Wb)[idx] = o;
  } else {
    const int n8 = M_DIM * (H_DIM / 8);                // 4,194,304 chunks
    const int stride = 2048 * 256;
    for (int idx = (bid - 2048) * 256 + threadIdx.x; idx < n8; idx += stride) {
      const float4* gp = (const float4*)(E + (size_t)idx * 8);
      float4 lo = gp[0], hi = gp[1];
      bf16x8 w;
      w[0] = (short)f2bf(lo.x); w[1] = (short)f2bf(lo.y);
      w[2] = (short)f2bf(lo.z); w[3] = (short)f2bf(lo.w);
      w[4] = (short)f2bf(hi.x); w[5] = (short)f2bf(hi.y);
      w[6] = (short)f2bf(hi.z); w[7] = (short)f2bf(hi.w);
      *(bf16x8*)(Eb + (size_t)idx * 8) = w;
    }
  }
}

// ---------------- K2: 256x256, k_att6 skeleton, 32x32x16 MFMA ----------------
// BM=256, BN=256, BK=64. 512 threads = 8 waves (2M x 4N), per-wave 128x64 tile
// = 4x2 frags of 32x32. Same LDS (2 x 64KB), same staging/sync as k_att6.
// A/B frag: row(col)=lane&31, k=(lane>>5)*8 + j (8 contiguous bf16) per kstep.
// C/D frag [m74/m101-verified]: col=lane&31, row=(reg&3)+8*(reg>>2)+4*(lane>>5).
#define A5_BM 256
#define A5_BN 256
#define A5_BUF 65536
#define NT_FAST 4      // n_tiles

__launch_bounds__(512, 2)
__global__ void k_att11(const unsigned short* __restrict__ Eb,
                        const unsigned short* __restrict__ Wb,
                        const float* __restrict__ Uh,
                        const float* __restrict__ vw,
                        float* __restrict__ att_p) {
  __shared__ __align__(16) char lds[2 * A5_BUF];   // 128 KB

  // XCD-friendly: blocks with same (bid&7) sit on one XCD
  const int bid = blockIdx.x;            // 0..511
  const int xj = bid & 7;
  const int q  = bid >> 3;               // 0..63
  const int n_tile = q & 3;              // 0..3
  const int m_tile = ((q >> 2) << 3) | xj;   // 0..127, bijective
  const int m0 = m_tile * A5_BM;
  const int n0 = n_tile * A5_BN;
  const int b  = m0 >> 10;

  const int tid  = threadIdx.x;          // 0..511
  const int wid  = tid >> 6;             // 0..7
  const int lane = tid & 63;
  const int wm = (wid >> 2) * 128;       // 0 / 128 (per-wave 128 rows)
  const int wn = (wid & 3) * 64;         // 0,64,128,192 (per-wave 64 cols)

  // Staging maps (linear LDS dest; inverse-swizzled global source; swizzled reads)
  size_t offA[4], offB[4];
  int ldsA[4], ldsB[4];
#pragma unroll
  for (int j = 0; j < 4; ++j) {
    const int chunk = j * 512 + tid;     // 0..2047 -> rows 0..255
    const int r  = chunk >> 3;
    const int c8 = (chunk & 7) ^ (r & 7);
    offA[j] = (size_t)(m0 + r) * H_DIM + c8 * 8;
    offB[j] = (size_t)(n0 + r) * H_DIM + c8 * 8;
    ldsA[j] = j * 8192 + wid * 1024;                 // A: [0, 32KB)
    ldsB[j] = 32768 + j * 8192 + wid * 1024;         // B: [32KB, 64KB)
  }

  auto stage = [&](int t) {              // 8 DMA loads -> buf (t&1)
    char* dst = lds + (t & 1) * A5_BUF;
    const size_t k0 = (size_t)t * 64;
#pragma unroll
    for (int j = 0; j < 4; ++j) gload16(Eb + offA[j] + k0, dst + ldsA[j]);
#pragma unroll
    for (int j = 0; j < 4; ++j) gload16(Wb + offB[j] + k0, dst + ldsB[j]);
  };

  const int c32 = lane & 31;             // frag row/col within 32
  const int khi = lane >> 5;             // k-group: 0 or 1 (8 bf16 each)

  f32x16 acc[4][2];
#pragma unroll
  for (int mf = 0; mf < 4; ++mf)
#pragma unroll
    for (int nf = 0; nf < 2; ++nf) acc[mf][nf] = (f32x16)(0.0f);

  stage(0);                              // 8 loads in flight

  for (int t = 0; t < 16; ++t) {
    // Own DMAs for tile t landed; barrier makes all waves' DMAs visible.
    asm volatile("s_waitcnt vmcnt(0)" ::: "memory");
    __builtin_amdgcn_s_barrier();
    asm volatile("" ::: "memory");       // keep ds_reads below the barrier

    if (t < 15) stage(t + 1);            // writes buf[(t+1)&1], protected by barrier

    const char* As = lds + (t & 1) * A5_BUF;
    const char* Bs = As + 32768;

    // 4 ksteps of K=16; frag addr: row*128 + (ks*16 + khi*8)*2, XOR-swizzled.
#pragma unroll
    for (int ks = 0; ks < 4; ++ks) {
      const int kb = ks * 32 + khi * 16;               // byte col within 128B row
      bf16x8 af[4], bfr[2];
#pragma unroll
      for (int mf = 0; mf < 4; ++mf) {
        const int row = wm + mf * 32 + c32;            // 0..255
        const int addr = (row * 128 + kb) ^ ((row & 7) << 4);
        af[mf] = *(const bf16x8*)(As + addr);
      }
#pragma unroll
      for (int nf = 0; nf < 2; ++nf) {
        const int row = wn + nf * 32 + c32;            // 0..255
        const int addr = (row * 128 + kb) ^ ((row & 7) << 4);
        bfr[nf] = *(const bf16x8*)(Bs + addr);
      }
      __builtin_amdgcn_s_setprio(1);
#pragma unroll
      for (int mf = 0; mf < 4; ++mf)
#pragma unroll
        for (int nf = 0; nf < 2; ++nf)
          acc[mf][nf] = __builtin_amdgcn_mfma_f32_32x32x16_bf16(af[mf], bfr[nf], acc[mf][nf], 0, 0, 0);
      __builtin_amdgcn_s_setprio(0);
    }
  }

  float* red = (float*)lds;   // [8 waves][128 rows]

  // Epilogue: tanh(acc + Uh)*v, reduce over this wave's 64 o's (2 frags x 32 cols).
  // C/D: col=lane&31, row=(reg&3)+8*(reg>>2)+4*(lane>>5)  [m74/m101-verified]
  float uh[2], vv[2];
#pragma unroll
  for (int nf = 0; nf < 2; ++nf) {
    const int o = n0 + wn + nf * 32 + c32;
    uh[nf] = Uh[b * H_DIM + o];
    vv[nf] = vw[o];
  }
#pragma unroll
  for (int mf = 0; mf < 4; ++mf) {
    float rs[16];
#pragma unroll
    for (int reg = 0; reg < 16; ++reg) {
      float s = 0.f;
#pragma unroll
      for (int nf = 0; nf < 2; ++nf) {
        const float x = acc[mf][nf][reg] + uh[nf];
        s += fast_tanh(x) * vv[nf];
      }
      rs[reg] = s;
    }
    // reduce across the 32 cols held by this 32-lane group (masks<32 keep khi half)
#pragma unroll
    for (int msk = 1; msk < 32; msk <<= 1) {
#pragma unroll
      for (int reg = 0; reg < 16; ++reg) rs[reg] += __shfl_xor(rs[reg], msk, 64);
    }
    if (c32 == 0) {
#pragma unroll
      for (int reg = 0; reg < 16; ++reg) {
        const int local = mf * 32 + (reg & 3) + 8 * (reg >> 2) + 4 * khi; // 0..127
        red[wid * 128 + local] = rs[reg];
      }
    }
  }
  __syncthreads();
  if (tid < 256) {
    const int mhalf = tid >> 7;          // waves {0..3} own rows 0..127, {4..7} rows 128..255
    const int loc = tid & 127;
    float sum = 0.f;
#pragma unroll
    for (int j = 0; j < 4; ++j) sum += red[(mhalf * 4 + j) * 128 + loc];
    att_p[(size_t)n_tile * M_DIM + m0 + tid] = sum;
  }
}

// ---------------- K3: fused softmax + context partials ----------------
__global__ void k_ctx_sm(const unsigned short* __restrict__ Eb,
                         const float* __restrict__ att_p,
                         float* __restrict__ alpha_out,
                         float* __restrict__ ctx_p) {
  const int bid = blockIdx.x;
  const int b  = bid >> 2;
  const int sq = bid & 3;
  const int tid = threadIdx.x;
  __shared__ float red[8];
  __shared__ float qa[256];

  float a[4];
  float mx = -1e30f;
#pragma unroll
  for (int i = 0; i < 4; ++i) {
    const int s = i * 256 + tid;
    float v = 0.f;
#pragma unroll
    for (int t = 0; t < NT_FAST; ++t) v += att_p[(size_t)t * M_DIM + b * S_DIM + s];
    a[i] = v;
    mx = fmaxf(mx, v);
  }
#pragma unroll
  for (int msk = 32; msk >= 1; msk >>= 1) mx = fmaxf(mx, __shfl_xor(mx, msk, 64));
  if ((tid & 63) == 0) red[tid >> 6] = mx;
  __syncthreads();
  mx = fmaxf(fmaxf(red[0], red[1]), fmaxf(red[2], red[3]));
  float sum = 0.f;
#pragma unroll
  for (int i = 0; i < 4; ++i) { a[i] = __expf(a[i] - mx); sum += a[i]; }
#pragma unroll
  for (int msk = 32; msk >= 1; msk >>= 1) sum += __shfl_xor(sum, msk, 64);
  if ((tid & 63) == 0) red[4 + (tid >> 6)] = sum;
  __syncthreads();
  const float inv = 1.f / (red[4] + red[5] + red[6] + red[7]);
  if (sq == 0) {
#pragma unroll
    for (int i = 0; i < 4; ++i) alpha_out[b * S_DIM + i * 256 + tid] = a[i] * inv;
  }
  qa[tid] = a[sq] * inv;
  __syncthreads();

  const int h = tid * 4;
  const unsigned short* ep = Eb + (size_t)b * S_DIM * H_DIM + (size_t)(sq * 256) * H_DIM + h;
  float4 acc = make_float4(0.f, 0.f, 0.f, 0.f);
  for (int s = 0; s < 256; ++s) {
    const float al = qa[s];
    ushort4 v = *(const ushort4*)(ep + (size_t)s * H_DIM);
    acc.x += al * bf2f(v.x);
    acc.y += al * bf2f(v.y);
    acc.z += al * bf2f(v.z);
    acc.w += al * bf2f(v.w);
  }
  *(float4*)&ctx_p[(size_t)sq * (B_DIM * H_DIM) + b * H_DIM + h] = acc;
}

// ---------------- K5: reduce context partials -> d_out ----------------
__global__ void k_ctx_reduce(const float* __restrict__ ctx_p, float* __restrict__ ctx) {
  const int i = blockIdx.x * 256 + threadIdx.x;
  ctx[i] = ctx_p[i] + ctx_p[32768 + i] + ctx_p[65536 + i] + ctx_p[98304 + i];
}

extern "C" void kernel_launch(void* const* d_in, const int* in_sizes, int n_in,
                              void* d_out, int out_size, void* d_ws, size_t ws_size,
                              hipStream_t stream) {
  (void)in_sizes; (void)n_in; (void)out_size; (void)ws_size;
  const float* dh  = (const float*)d_in[0];
  const float* enc = (const float*)d_in[1];
  const float* Uw  = (const float*)d_in[2];
  const float* Ww  = (const float*)d_in[3];
  const float* vw  = (const float*)d_in[4];
  float* ctx_out = (float*)d_out;                 // [32,1024]
  float* alpha   = (float*)d_out + M_DIM;         // [32,1024]

  char* ws = (char*)d_ws;
  const size_t EB_BYTES = (size_t)M_DIM * H_DIM * 2;            // 64 MiB

  unsigned short* Eb = (unsigned short*)ws;
  unsigned short* Wb = (unsigned short*)(ws + EB_BYTES);
  float* Uh    = (float*)(ws + EB_BYTES + (2u << 20));
  float* att_p = (float*)(ws + EB_BYTES + (2u << 20) + (128u << 10));
  float* ctx_p = (float*)(ws + EB_BYTES + (2u << 20) + (128u << 10) + (1u << 20));

  k_prep_all<<<4096, 256, 0, stream>>>(enc, Eb, Ww, Wb, dh, Uw, Uh);
  k_att11<<<512, 512, 0, stream>>>(Eb, Wb, Uh, vw, att_p);
  k_ctx_sm<<<128, 256, 0, stream>>>(Eb, att_p, alpha, ctx_p);
  k_ctx_reduce<<<128, 256, 0, stream>>>(ctx_p, ctx_out);
}

// Round 15
// 129.076 us; speedup vs baseline: 1.3042x; 1.0940x over previous
//
#include <hip/hip_runtime.h>
#include <hip/hip_bf16.h>
#include <cstdint>
#include <cstddef>

#define B_DIM 32
#define S_DIM 1024
#define H_DIM 1024
#define M_DIM (B_DIM * S_DIM)   // 32768

typedef __attribute__((ext_vector_type(8))) short bf16x8;
typedef __attribute__((ext_vector_type(4))) float f32x4;

// round-to-nearest-even fp32 -> bf16 (bit trick; no NaN inputs here)
static __device__ __forceinline__ unsigned short f2bf(float f) {
  unsigned u = __float_as_uint(f);
  u = (u + 0x7FFFu + ((u >> 16) & 1u)) >> 16;
  return (unsigned short)u;
}
static __device__ __forceinline__ float bf2f(unsigned short u) {
  return __uint_as_float(((unsigned)u) << 16);
}
// exact identity tanh(x) = 1 - 2/(exp(2x)+1)
static __device__ __forceinline__ float fast_tanh(float x) {
  return 1.f - 2.f / (__expf(2.f * x) + 1.f);
}

// async global(16B/lane) -> LDS, wave-uniform LDS base, per-lane global addr
static __device__ __forceinline__ void gload16(const unsigned short* g, char* l) {
  __builtin_amdgcn_global_load_lds(
      (const __attribute__((address_space(1))) unsigned int*)g,
      (__attribute__((address_space(3))) unsigned int*)l, 16, 0, 0);
}

// ---------------- K_prep_all ----------------
// Blocks 0..1023: U_h (latency-bound, FIRST so it overlaps the convert).
// Blocks 1024..2047: W -> bf16. Blocks 2048..4095: enc -> bf16 (grid-stride).
__global__ void k_prep_all(const float* __restrict__ E, unsigned short* __restrict__ Eb,
                           const float* __restrict__ W, unsigned short* __restrict__ Wb,
                           const float* __restrict__ dh, const float* __restrict__ Uw,
                           float* __restrict__ Uh) {
  const int bid = blockIdx.x;
  if (bid < 1024) {
    const int wave = threadIdx.x >> 6;
    const int lane = threadIdx.x & 63;
    const int o = bid;                                 // 0..1023
    float uw[16];
#pragma unroll
    for (int k = 0; k < 16; ++k) uw[k] = Uw[o * H_DIM + k * 64 + lane];
#pragma unroll
    for (int bb = 0; bb < 8; ++bb) {
      const int b = wave * 8 + bb;                     // 0..31
      float acc = 0.f;
#pragma unroll
      for (int k = 0; k < 16; ++k) acc += uw[k] * dh[b * H_DIM + k * 64 + lane];
#pragma unroll
      for (int msk = 32; msk >= 1; msk >>= 1) acc += __shfl_xor(acc, msk, 64);
      if (lane == 0) Uh[b * H_DIM + o] = acc;
    }
  } else if (bid < 2048) {
    const int idx = (bid - 1024) * 256 + threadIdx.x;  // 0 .. 262143
    float4 v = ((const float4*)W)[idx];
    ushort4 o;
    o.x = f2bf(v.x); o.y = f2bf(v.y); o.z = f2bf(v.z); o.w = f2bf(v.w);
    ((ushort4*)Wb)[idx] = o;
  } else {
    const int n8 = M_DIM * (H_DIM / 8);                // 4,194,304 chunks
    const int stride = 2048 * 256;
    for (int idx = (bid - 2048) * 256 + threadIdx.x; idx < n8; idx += stride) {
      const float4* gp = (const float4*)(E + (size_t)idx * 8);
      float4 lo = gp[0], hi = gp[1];
      bf16x8 w;
      w[0] = (short)f2bf(lo.x); w[1] = (short)f2bf(lo.y);
      w[2] = (short)f2bf(lo.z); w[3] = (short)f2bf(lo.w);
      w[4] = (short)f2bf(hi.x); w[5] = (short)f2bf(hi.y);
      w[6] = (short)f2bf(hi.z); w[7] = (short)f2bf(hi.w);
      *(bf16x8*)(Eb + (size_t)idx * 8) = w;
    }
  }
}

// ---------------- K2: 256x256 single-barrier-per-tile fused att GEMM ----------------
// (round-8/12 k_att6, the measured optimum of this structure family: 81us,
//  MfmaUtil 36%, VGPR 112, no spill, 0 bank conflicts)
#define A5_BM 256
#define A5_BN 256
#define A5_BUF 65536
#define NT_FAST 4      // n_tiles

__launch_bounds__(512, 2)
__global__ void k_att6(const unsigned short* __restrict__ Eb,
                       const unsigned short* __restrict__ Wb,
                       const float* __restrict__ Uh,
                       const float* __restrict__ vw,
                       float* __restrict__ att_p) {
  __shared__ __align__(16) char lds[2 * A5_BUF];   // 128 KB

  // XCD-friendly: blocks with same (bid&7) sit on one XCD
  const int bid = blockIdx.x;            // 0..511
  const int xj = bid & 7;
  const int q  = bid >> 3;               // 0..63
  const int n_tile = q & 3;              // 0..3
  const int m_tile = ((q >> 2) << 3) | xj;   // 0..127, bijective
  const int m0 = m_tile * A5_BM;
  const int n0 = n_tile * A5_BN;
  const int b  = m0 >> 10;

  const int tid  = threadIdx.x;          // 0..511
  const int wid  = tid >> 6;             // 0..7
  const int lane = tid & 63;
  const int wm = (wid >> 2) * 128;       // 0 / 128 (per-wave 128 rows)
  const int wn = (wid & 3) * 64;         // 0,64,128,192 (per-wave 64 cols)

  // Staging maps (linear LDS dest; inverse-swizzled global source; swizzled reads)
  size_t offA[4], offB[4];
  int ldsA[4], ldsB[4];
#pragma unroll
  for (int j = 0; j < 4; ++j) {
    const int chunk = j * 512 + tid;     // 0..2047 -> rows 0..255
    const int r  = chunk >> 3;
    const int c8 = (chunk & 7) ^ (r & 7);
    offA[j] = (size_t)(m0 + r) * H_DIM + c8 * 8;
    offB[j] = (size_t)(n0 + r) * H_DIM + c8 * 8;
    ldsA[j] = j * 8192 + wid * 1024;                 // A: [0, 32KB)
    ldsB[j] = 32768 + j * 8192 + wid * 1024;         // B: [32KB, 64KB)
  }

  auto stage = [&](int t) {              // 8 DMA loads -> buf (t&1)
    char* dst = lds + (t & 1) * A5_BUF;
    const size_t k0 = (size_t)t * 64;
#pragma unroll
    for (int j = 0; j < 4; ++j) gload16(Eb + offA[j] + k0, dst + ldsA[j]);
#pragma unroll
    for (int j = 0; j < 4; ++j) gload16(Wb + offB[j] + k0, dst + ldsB[j]);
  };

  const int fr_row = lane & 15;
  const int fr_k8  = lane >> 4;

  f32x4 acc[8][4];
#pragma unroll
  for (int mf = 0; mf < 8; ++mf)
#pragma unroll
    for (int nf = 0; nf < 4; ++nf) acc[mf][nf] = (f32x4)(0.0f);

  stage(0);                              // 8 loads in flight

  for (int t = 0; t < 16; ++t) {
    // Own DMAs for tile t landed; barrier makes all waves' DMAs visible.
    // Issue->wait distance is a full K-tile (~3000 cy) so this drain is ~free.
    asm volatile("s_waitcnt vmcnt(0)" ::: "memory");
    __builtin_amdgcn_s_barrier();
    asm volatile("" ::: "memory");       // keep ds_reads below the barrier

    // Safe: buf[(t+1)&1] was last READ in iter t-1; every wave passed this
    // barrier => finished iter t-1 entirely.
    if (t < 15) stage(t + 1);

    const char* As = lds + (t & 1) * A5_BUF;
    const char* Bs = As + 32768;

    // Both kh frag sets are separate SSA values -> compiler interleaves the
    // kh=1 ds_reads (and the DMA issue) under the kh=0 MFMA cluster with
    // fine-grained lgkmcnt. No barrier between reads and MFMA.
#pragma unroll
    for (int kh = 0; kh < 2; ++kh) {
      const int kb = kh * 32 + fr_k8 * 8;
      bf16x8 af[8], bfr[4];
#pragma unroll
      for (int mf = 0; mf < 8; ++mf) {
        const int row = wm + mf * 16 + fr_row;               // 0..255
        const int addr = (row * 128 + kb * 2) ^ ((row & 7) << 4);
        af[mf] = *(const bf16x8*)(As + addr);
      }
#pragma unroll
      for (int nf = 0; nf < 4; ++nf) {
        const int row = wn + nf * 16 + fr_row;               // 0..255
        const int addr = (row * 128 + kb * 2) ^ ((row & 7) << 4);
        bfr[nf] = *(const bf16x8*)(Bs + addr);
      }
      __builtin_amdgcn_s_setprio(1);
#pragma unroll
      for (int mf = 0; mf < 8; ++mf)
#pragma unroll
        for (int nf = 0; nf < 4; ++nf)
          acc[mf][nf] = __builtin_amdgcn_mfma_f32_16x16x32_bf16(af[mf], bfr[nf], acc[mf][nf], 0, 0, 0);
      __builtin_amdgcn_s_setprio(0);
    }
  }

  float* red = (float*)lds;   // [8 waves][128 rows]

  // Epilogue: tanh(acc + Uh)*v, reduce over this wave's 64 o's.
  // D frag: col = lane&15 (n), row = (lane>>4)*4 + reg (m)
  const int col = lane & 15;
  const int rhi = lane >> 4;
  float uh[4], vv[4];
#pragma unroll
  for (int nf = 0; nf < 4; ++nf) {
    const int o = n0 + wn + nf * 16 + col;
    uh[nf] = Uh[b * H_DIM + o];
    vv[nf] = vw[o];
  }
#pragma unroll
  for (int mf = 0; mf < 8; ++mf) {
    float rs[4];
#pragma unroll
    for (int jj = 0; jj < 4; ++jj) {
      float s = 0.f;
#pragma unroll
      for (int nf = 0; nf < 4; ++nf) {
        const float x = acc[mf][nf][jj] + uh[nf];
        s += fast_tanh(x) * vv[nf];
      }
      rs[jj] = s;
    }
#pragma unroll
    for (int msk = 1; msk < 16; msk <<= 1) {
#pragma unroll
      for (int jj = 0; jj < 4; ++jj) rs[jj] += __shfl_xor(rs[jj], msk, 64);
    }
    if (col == 0) {
#pragma unroll
      for (int jj = 0; jj < 4; ++jj) {
        const int local = mf * 16 + rhi * 4 + jj;   // row within wave's 128
        red[wid * 128 + local] = rs[jj];
      }
    }
  }
  __syncthreads();
  if (tid < 256) {
    const int mhalf = tid >> 7;          // waves {0..3} own rows 0..127, {4..7} rows 128..255
    const int loc = tid & 127;
    float sum = 0.f;
#pragma unroll
    for (int j = 0; j < 4; ++j) sum += red[(mhalf * 4 + j) * 128 + loc];
    att_p[(size_t)n_tile * M_DIM + m0 + tid] = sum;
  }
}

// ---------------- K3: fused softmax + context partials ----------------
__global__ void k_ctx_sm(const unsigned short* __restrict__ Eb,
                         const float* __restrict__ att_p,
                         float* __restrict__ alpha_out,
                         float* __restrict__ ctx_p) {
  const int bid = blockIdx.x;
  const int b  = bid >> 2;
  const int sq = bid & 3;
  const int tid = threadIdx.x;
  __shared__ float red[8];
  __shared__ float qa[256];

  float a[4];
  float mx = -1e30f;
#pragma unroll
  for (int i = 0; i < 4; ++i) {
    const int s = i * 256 + tid;
    float v = 0.f;
#pragma unroll
    for (int t = 0; t < NT_FAST; ++t) v += att_p[(size_t)t * M_DIM + b * S_DIM + s];
    a[i] = v;
    mx = fmaxf(mx, v);
  }
#pragma unroll
  for (int msk = 32; msk >= 1; msk >>= 1) mx = fmaxf(mx, __shfl_xor(mx, msk, 64));
  if ((tid & 63) == 0) red[tid >> 6] = mx;
  __syncthreads();
  mx = fmaxf(fmaxf(red[0], red[1]), fmaxf(red[2], red[3]));
  float sum = 0.f;
#pragma unroll
  for (int i = 0; i < 4; ++i) { a[i] = __expf(a[i] - mx); sum += a[i]; }
#pragma unroll
  for (int msk = 32; msk >= 1; msk >>= 1) sum += __shfl_xor(sum, msk, 64);
  if ((tid & 63) == 0) red[4 + (tid >> 6)] = sum;
  __syncthreads();
  const float inv = 1.f / (red[4] + red[5] + red[6] + red[7]);
  if (sq == 0) {
#pragma unroll
    for (int i = 0; i < 4; ++i) alpha_out[b * S_DIM + i * 256 + tid] = a[i] * inv;
  }
  qa[tid] = a[sq] * inv;
  __syncthreads();

  const int h = tid * 4;
  const unsigned short* ep = Eb + (size_t)b * S_DIM * H_DIM + (size_t)(sq * 256) * H_DIM + h;
  float4 acc = make_float4(0.f, 0.f, 0.f, 0.f);
  for (int s = 0; s < 256; ++s) {
    const float al = qa[s];
    ushort4 v = *(const ushort4*)(ep + (size_t)s * H_DIM);
    acc.x += al * bf2f(v.x);
    acc.y += al * bf2f(v.y);
    acc.z += al * bf2f(v.z);
    acc.w += al * bf2f(v.w);
  }
  *(float4*)&ctx_p[(size_t)sq * (B_DIM * H_DIM) + b * H_DIM + h] = acc;
}

// ---------------- K5: reduce context partials -> d_out ----------------
__global__ void k_ctx_reduce(const float* __restrict__ ctx_p, float* __restrict__ ctx) {
  const int i = blockIdx.x * 256 + threadIdx.x;
  ctx[i] = ctx_p[i] + ctx_p[32768 + i] + ctx_p[65536 + i] + ctx_p[98304 + i];
}

extern "C" void kernel_launch(void* const* d_in, const int* in_sizes, int n_in,
                              void* d_out, int out_size, void* d_ws, size_t ws_size,
                              hipStream_t stream) {
  (void)in_sizes; (void)n_in; (void)out_size; (void)ws_size;
  const float* dh  = (const float*)d_in[0];
  const float* enc = (const float*)d_in[1];
  const float* Uw  = (const float*)d_in[2];
  const float* Ww  = (const float*)d_in[3];
  const float* vw  = (const float*)d_in[4];
  float* ctx_out = (float*)d_out;                 // [32,1024]
  float* alpha   = (float*)d_out + M_DIM;         // [32,1024]

  char* ws = (char*)d_ws;
  const size_t EB_BYTES = (size_t)M_DIM * H_DIM * 2;            // 64 MiB

  unsigned short* Eb = (unsigned short*)ws;
  unsigned short* Wb = (unsigned short*)(ws + EB_BYTES);
  float* Uh    = (float*)(ws + EB_BYTES + (2u << 20));
  float* att_p = (float*)(ws + EB_BYTES + (2u << 20) + (128u << 10));
  float* ctx_p = (float*)(ws + EB_BYTES + (2u << 20) + (128u << 10) + (1u << 20));

  k_prep_all<<<4096, 256, 0, stream>>>(enc, Eb, Ww, Wb, dh, Uw, Uh);
  k_att6<<<512, 512, 0, stream>>>(Eb, Wb, Uh, vw, att_p);
  k_ctx_sm<<<128, 256, 0, stream>>>(Eb, att_p, alpha, ctx_p);
  k_ctx_reduce<<<128, 256, 0, stream>>>(ctx_p, ctx_out);
}